// Round 12
// baseline (61443.573 us; speedup 1.0000x reference)
//
#include <hip/hip_runtime.h>
#include <cstddef>

// SafetyReflexSNN: 5-layer LIF SNN, B=128, T=512. PASSED r11 (absmax 0.0).
//
// NUMERICS (FROZEN — bit-exact match to harness numpy reference):
//  - per C element: fmaf chain, ascending k, single accumulator
//  - K=1024: two 512-chains folded by ONE __fadd_rn; K=512: single chain
//  - layer 2: W2a-chain and W2b-chain combined by ONE __fadd_rn
//  - LIF: __fmul_rn then __fadd_rn (no contraction); v*(1-s) via __fmul_rn
//
// SPEED (round 12): LDS-free GEMM. r11 was LDS-BW-bound (~4B/MAC vs
// 128B/cyc/CU -> 25% VALU, 15 TF). New structure: lane = o, wave holds E
// b-rows' accumulators in VGPRs; A (spikes/x) loaded via SCALAR path
// (lane-invariant address -> s_load), W pre-transposed (WT[k][o]) so the
// single vector load per k is coalesced from L2-resident WT. Per k:
// 1 vmem + E s_load + E v_fmac -> VALU-bound. E per layer (8/4/2/4/8)
// balances all 2080 waves at 4096 FMA instrs each (~2 waves/SIMD).

#define NT 512

enum : size_t {
  FOFF_V0  = 0,                          // [128][1024]
  FOFF_V1  = FOFF_V0 + 128 * 1024,
  FOFF_V2  = FOFF_V1 + 128 * 1024,
  FOFF_V3  = FOFF_V2 + 128 * 1024,       // [128][512]
  FOFF_VO  = FOFF_V3 + 128 * 512,        // [128][128]
  FOFF_CNT = FOFF_VO + 128 * 128,        // [128][128]
  FOFF_S0  = FOFF_CNT + 128 * 128,       // 2 x [128][1024]
  FOFF_S1  = FOFF_S0 + 2 * 128 * 1024,
  FOFF_S2  = FOFF_S1 + 2 * 128 * 1024,
  FOFF_S3  = FOFF_S2 + 2 * 128 * 1024,   // 2 x [128][512]
  ZERO_END = FOFF_S3 + 2 * 128 * 512,
  FOFF_W0T = ZERO_END,                   // [512][1024]  (WT[k][o])
  FOFF_W1T = FOFF_W0T + 512 * 1024,      // [1024][1024]
  FOFF_W2AT = FOFF_W1T + 1024 * 1024,
  FOFF_W2BT = FOFF_W2AT + 1024 * 1024,
  FOFF_W3T = FOFF_W2BT + 1024 * 1024,    // [1024][512]
  FOFF_W4T = FOFF_W3T + 1024 * 512,      // [512][128]
  WS_END   = FOFF_W4T + 512 * 128        // ~5.67M floats (~22.7 MB)
};

__global__ __launch_bounds__(256) void init_kernel(float* __restrict__ wf) {
  size_t i = (size_t)blockIdx.x * blockDim.x + threadIdx.x;
  size_t stride = (size_t)gridDim.x * blockDim.x;
  for (size_t j = i; j < ZERO_END; j += stride) wf[j] = 0.0f;
}

// dst[c][r] = src[r][c] ; src is [R][C]. dst-coalesced.
__global__ __launch_bounds__(256) void transpose_kernel(
    const float* __restrict__ src, float* __restrict__ dst, int R, int C) {
  size_t total = (size_t)R * C;
  for (size_t idx = (size_t)blockIdx.x * 256 + threadIdx.x; idx < total;
       idx += (size_t)gridDim.x * 256) {
    size_t c = idx / (size_t)R, r = idx - c * (size_t)R;
    dst[idx] = src[r * (size_t)C + c];
  }
}

// Chain segment [k0,k1): pan[e] = fmaf-chain over k of A[b0+e][k] * WT[k][o].
// A addresses are lane-invariant (scalar loads); WT load is lane-coalesced.
template <int E>
__device__ __forceinline__ void seg(
    const float* __restrict__ A, size_t aStr, int b0,
    const float* __restrict__ WT, int N, int o,
    int k0, int k1, float (&pan)[E])
{
#pragma unroll 8
  for (int k = k0; k < k1; ++k) {
    float wv = WT[(size_t)k * N + o];
#pragma unroll
    for (int e = 0; e < E; ++e)
      pan[e] = fmaf(A[(size_t)(b0 + e) * aStr + k], wv, pan[e]);
  }
}

// Full gemm for E b-rows at output column o. K=1024 folds at 512 (FROZEN).
template <int E>
__device__ __forceinline__ void gemm(
    const float* __restrict__ A, size_t aStr, int b0,
    const float* __restrict__ WT, int N, int o, int K,
    float (&acc)[E])
{
  float pan[E];
#pragma unroll
  for (int e = 0; e < E; ++e) pan[e] = 0.f;
  if (K == 1024) {
    seg<E>(A, aStr, b0, WT, N, o, 0, 512, pan);
    float c1[E];
#pragma unroll
    for (int e = 0; e < E; ++e) { c1[e] = pan[e]; pan[e] = 0.f; }
    seg<E>(A, aStr, b0, WT, N, o, 512, 1024, pan);
#pragma unroll
    for (int e = 0; e < E; ++e) acc[e] = __fadd_rn(c1[e], pan[e]);
  } else {
    seg<E>(A, aStr, b0, WT, N, o, 0, K, pan);
#pragma unroll
    for (int e = 0; e < E; ++e) acc[e] = pan[e];
  }
}

template <int E, bool LAST>
__device__ __forceinline__ void lif_ep(
    float (&cur)[E], float* __restrict__ V, int N,
    float alpha, float vth, int b0, int o,
    float* __restrict__ sOut,
    float* __restrict__ out, float* __restrict__ counts, int t)
{
#pragma unroll
  for (int e = 0; e < E; ++e) {
    int b = b0 + e;
    float* vp = V + (size_t)b * N + o;
    float vv = __fadd_rn(__fmul_rn(alpha, *vp), cur[e]);
    float s = (vv >= vth) ? 1.0f : 0.0f;
    *vp = __fmul_rn(vv, __fsub_rn(1.0f, s));
    if (!LAST) {
      sOut[(size_t)b * N + o] = s;
    } else {
      out[(size_t)b * (NT * 128) + (size_t)t * 128 + o] = s;
      float* cp = counts + b * 128 + o;
      *cp = __fadd_rn(*cp, s);
    }
  }
}

// Blocks: L0 [0,64)=16ocol x 4bq  | L1 [64,192)=16 x 8 | L2 [192,448)=16 x 16
//         L3 [448,512)=8 x 8      | L4 [512,520)=2 x 4
__global__ __launch_bounds__(256) void phase_kernel(
    const float* __restrict__ x, float* __restrict__ wf,
    float* __restrict__ out, int p)
{
  const int blk = blockIdx.x;
  const int wid = __builtin_amdgcn_readfirstlane((int)(threadIdx.x >> 6));
  const int lane = threadIdx.x & 63;
  const int cur = p & 1, prev = cur ^ 1;

  float* s0 = wf + FOFF_S0;  float* s1 = wf + FOFF_S1;
  float* s2 = wf + FOFF_S2;  float* s3 = wf + FOFF_S3;

  if (blk < 64) {            // L0: E=8, K=512, N=1024, A = x
    int t = p; if (t >= NT) return;
    int ocol = blk >> 2, bq = blk & 3;
    int b0 = (bq * 4 + wid) * 8;
    int o = ocol * 64 + lane;
    float acc[8];
    gemm<8>(x + (size_t)t * 512, (size_t)NT * 512, b0, wf + FOFF_W0T, 1024, o, 512, acc);
    lif_ep<8, false>(acc, wf + FOFF_V0, 1024, 0.9f, 0.5f, b0, o,
                     s0 + (size_t)cur * 128 * 1024, nullptr, nullptr, 0);
  } else if (blk < 192) {    // L1: E=4, K=1024, N=1024, A = s0
    int t = p - 1; if (t < 0 || t >= NT) return;
    int r = blk - 64; int ocol = r >> 3, bq = r & 7;
    int b0 = (bq * 4 + wid) * 4;
    int o = ocol * 64 + lane;
    float acc[4];
    gemm<4>(s0 + (size_t)prev * 128 * 1024, 1024, b0, wf + FOFF_W1T, 1024, o, 1024, acc);
    lif_ep<4, false>(acc, wf + FOFF_V1, 1024, 0.95f, 0.5f, b0, o,
                     s1 + (size_t)cur * 128 * 1024, nullptr, nullptr, 0);
  } else if (blk < 448) {    // L2: E=2, two K=1024 gemms, N=1024
    int t = p - 2; if (t < 0 || t >= NT) return;
    int r = blk - 192; int ocol = r >> 4, bq = r & 15;
    int b0 = (bq * 4 + wid) * 2;
    int o = ocol * 64 + lane;
    float a1[2], a2[2];
    gemm<2>(s1 + (size_t)prev * 128 * 1024, 1024, b0, wf + FOFF_W2AT, 1024, o, 1024, a1);
    gemm<2>(s2 + (size_t)prev * 128 * 1024, 1024, b0, wf + FOFF_W2BT, 1024, o, 1024, a2);
    float cu[2];
#pragma unroll
    for (int e = 0; e < 2; ++e) cu[e] = __fadd_rn(a1[e], a2[e]);
    lif_ep<2, false>(cu, wf + FOFF_V2, 1024, 0.93f, 0.5f, b0, o,
                     s2 + (size_t)cur * 128 * 1024, nullptr, nullptr, 0);
  } else if (blk < 512) {    // L3: E=4, K=1024, N=512, A = s2
    int t = p - 3; if (t < 0 || t >= NT) return;
    int r = blk - 448; int ocol = r >> 3, bq = r & 7;
    int b0 = (bq * 4 + wid) * 4;
    int o = ocol * 64 + lane;
    float acc[4];
    gemm<4>(s2 + (size_t)prev * 128 * 1024, 1024, b0, wf + FOFF_W3T, 512, o, 1024, acc);
    lif_ep<4, false>(acc, wf + FOFF_V3, 512, 0.9f, 0.5f, b0, o,
                     s3 + (size_t)cur * 128 * 512, nullptr, nullptr, 0);
  } else {                   // L4: E=8, K=512, N=128, A = s3, epilogue->out
    int t = p - 4; if (t < 0 || t >= NT) return;
    int r = blk - 512; int ocol = r >> 2, bq = r & 3;
    int b0 = (bq * 4 + wid) * 8;
    int o = ocol * 64 + lane;
    float acc[8];
    gemm<8>(s3 + (size_t)prev * 128 * 512, 512, b0, wf + FOFF_W4T, 128, o, 512, acc);
    lif_ep<8, true>(acc, wf + FOFF_VO, 128, 0.82f, 0.8f, b0, o,
                    nullptr, out, wf + FOFF_CNT, t);
  }
}

__global__ __launch_bounds__(256) void fin_kernel(const float* __restrict__ counts,
                                                  float* __restrict__ out) {
  int i = blockIdx.x * blockDim.x + threadIdx.x;
  if (i < 128 * 128) out[(size_t)128 * NT * 128 + i] = counts[i];
}

extern "C" void kernel_launch(void* const* d_in, const int* in_sizes, int n_in,
                              void* d_out, int out_size, void* d_ws, size_t ws_size,
                              hipStream_t stream) {
  const float* x   = (const float*)d_in[0];
  const float* W0  = (const float*)d_in[1];
  const float* W1  = (const float*)d_in[2];
  const float* W2a = (const float*)d_in[3];
  const float* W2b = (const float*)d_in[4];
  const float* W3  = (const float*)d_in[5];
  const float* W4  = (const float*)d_in[6];
  float* wf  = (float*)d_ws;
  float* out = (float*)d_out;

  init_kernel<<<256, 256, 0, stream>>>(wf);
  // WT[k][o] = W[o][k] for each weight matrix (value-exact copy)
  transpose_kernel<<<1024, 256, 0, stream>>>(W0,  wf + FOFF_W0T, 1024, 512);
  transpose_kernel<<<1024, 256, 0, stream>>>(W1,  wf + FOFF_W1T, 1024, 1024);
  transpose_kernel<<<1024, 256, 0, stream>>>(W2a, wf + FOFF_W2AT, 1024, 1024);
  transpose_kernel<<<1024, 256, 0, stream>>>(W2b, wf + FOFF_W2BT, 1024, 1024);
  transpose_kernel<<<1024, 256, 0, stream>>>(W3,  wf + FOFF_W3T, 512, 1024);
  transpose_kernel<<<256, 256, 0, stream>>>(W4,  wf + FOFF_W4T, 128, 512);
  for (int p = 0; p < NT + 4; ++p) {
    phase_kernel<<<520, 256, 0, stream>>>(x, wf, out, p);
  }
  fin_kernel<<<64, 256, 0, stream>>>(wf + FOFF_CNT, out);
}

// Round 13
// 59384.711 us; speedup vs baseline: 1.0347x; 1.0347x over previous
//
#include <hip/hip_runtime.h>
#include <cstddef>

// SafetyReflexSNN: 5-layer LIF SNN, B=128, T=512. r11 PASSED (absmax 0.0).
//
// NUMERICS (FROZEN — bit-exact vs harness numpy reference):
//  - per C element: fmaf chain, ascending k, single accumulator
//  - K=1024: two 512-chains folded by ONE __fadd_rn; K=512: single chain
//  - layer 2: W2a-chain + W2b-chain combined by ONE __fadd_rn
//  - LIF: __fmul_rn then __fadd_rn; v*(1-s) via __fmul_rn
//
// SPEED (round 13): lane=b, E o-columns per lane in VGPRs.
//  - A staged in LDS k-major [64k][64b+1pad]: 1 ds_read_b32/k feeds E fmas
//    (r11 was 1 ds_read/fma -> LDS-bound at 25% VALU)
//  - W via scalar path: wave-uniform o -> s_load_dwordx4 of W[o][k..k+3]
//    from the ORIGINAL layout; scalar pipe overlaps VALU; W read once per
//    b-half per phase (r12's 740MB/phase W re-reads -> 34MB/phase)
//  - 128-thr blocks, 592 blocks/phase -> 1184 waves (~1.16/SIMD), all CUs

#define NT 512

enum : size_t {
  FOFF_V0  = 0,                          // [128][1024]
  FOFF_V1  = FOFF_V0 + 128 * 1024,
  FOFF_V2  = FOFF_V1 + 128 * 1024,
  FOFF_V3  = FOFF_V2 + 128 * 1024,       // [128][512]
  FOFF_VO  = FOFF_V3 + 128 * 512,        // [128][128]
  FOFF_CNT = FOFF_VO + 128 * 128,        // [128][128]
  FOFF_S0  = FOFF_CNT + 128 * 128,       // 2 x [128][1024]
  FOFF_S1  = FOFF_S0 + 2 * 128 * 1024,
  FOFF_S2  = FOFF_S1 + 2 * 128 * 1024,
  FOFF_S3  = FOFF_S2 + 2 * 128 * 1024,   // 2 x [128][512]
  ZERO_END = FOFF_S3 + 2 * 128 * 512
};

__global__ __launch_bounds__(256) void init_kernel(float* __restrict__ wf) {
  size_t i = (size_t)blockIdx.x * blockDim.x + threadIdx.x;
  size_t stride = (size_t)gridDim.x * blockDim.x;
  for (size_t j = i; j < ZERO_END; j += stride) wf[j] = 0.0f;
}

// GEMM for one wave: E output columns o0..o0+E-1, 64 batch rows (lane=b).
// A [128][aStr-rows] staged per 64k-chunk into lds k-major [k][b] stride 65.
// W original layout [N][K], scalar loads. FROZEN fold at k=512 for K=1024.
template <int E>
__device__ __forceinline__ void gemm_wave(
    const float* __restrict__ A, size_t aStr, int b0,
    const float* __restrict__ W, int K, int o0,
    float* __restrict__ lds, float (&acc)[E])
{
  const int tid = threadIdx.x;       // 0..127
  const int lane = tid & 63;
  float pan[E], c1[E];
#pragma unroll
  for (int e = 0; e < E; ++e) { pan[e] = 0.f; c1[e] = 0.f; }
  const int nchunk = K >> 6;
  for (int c = 0; c < nchunk; ++c) {
    const int kb = c << 6;
    __syncthreads();
    // stage A[b0..b0+63][kb..kb+63] -> lds[k][b] (stride 65, 2-way banks)
#pragma unroll
    for (int s = 0; s < 8; ++s) {
      int slot = tid + (s << 7);       // 0..1023 float4 slots
      int b = slot >> 4;
      int kq = (slot & 15) << 2;
      float4 g = *(const float4*)(A + (size_t)(b0 + b) * aStr + kb + kq);
      lds[(kq + 0) * 65 + b] = g.x;
      lds[(kq + 1) * 65 + b] = g.y;
      lds[(kq + 2) * 65 + b] = g.z;
      lds[(kq + 3) * 65 + b] = g.w;
    }
    __syncthreads();
    if (K == 1024 && c == 8) {         // FROZEN fold boundary at k=512
#pragma unroll
      for (int e = 0; e < E; ++e) { c1[e] = pan[e]; pan[e] = 0.f; }
    }
#pragma unroll 4
    for (int k4 = 0; k4 < 16; ++k4) {
      float a0 = lds[(k4 * 4 + 0) * 65 + lane];
      float a1 = lds[(k4 * 4 + 1) * 65 + lane];
      float a2 = lds[(k4 * 4 + 2) * 65 + lane];
      float a3 = lds[(k4 * 4 + 3) * 65 + lane];
#pragma unroll
      for (int j = 0; j < E; ++j) {
        // o0 wave-uniform -> scalar loads on the SMEM pipe
        float4 w = *(const float4*)(W + (size_t)(o0 + j) * K + kb + k4 * 4);
        pan[j] = fmaf(a0, w.x, pan[j]);
        pan[j] = fmaf(a1, w.y, pan[j]);
        pan[j] = fmaf(a2, w.z, pan[j]);
        pan[j] = fmaf(a3, w.w, pan[j]);
      }
    }
  }
#pragma unroll
  for (int e = 0; e < E; ++e)
    acc[e] = (K == 1024) ? __fadd_rn(c1[e], pan[e]) : pan[e];
}

template <int E, bool LAST>
__device__ __forceinline__ void lif_ep(
    float (&cur)[E], float* __restrict__ V, int N,
    float alpha, float vth, int b, int o0,
    float* __restrict__ sOut,
    float* __restrict__ out, float* __restrict__ counts, int t)
{
#pragma unroll
  for (int j = 0; j < E; ++j) {
    int o = o0 + j;
    float* vp = V + (size_t)b * N + o;
    float vv = __fadd_rn(__fmul_rn(alpha, *vp), cur[j]);
    float s = (vv >= vth) ? 1.0f : 0.0f;
    *vp = __fmul_rn(vv, __fsub_rn(1.0f, s));
    if (!LAST) {
      sOut[(size_t)b * N + o] = s;
    } else {
      out[(size_t)b * (NT * 128) + (size_t)t * 128 + o] = s;
      float* cp = counts + b * 128 + o;
      *cp = __fadd_rn(*cp, s);
    }
  }
}

// Blocks (128 thr = 2 waves): L0 [0,128) L1 [128,256) L2 [256,512)
//                             L3 [512,576) L4 [576,592)
__global__ __launch_bounds__(128) void phase_kernel(
    const float* __restrict__ x,
    const float* __restrict__ W0, const float* __restrict__ W1,
    const float* __restrict__ W2a, const float* __restrict__ W2b,
    const float* __restrict__ W3, const float* __restrict__ W4,
    float* __restrict__ wf, float* __restrict__ out, int p)
{
  __shared__ float lds[64 * 65];
  const int blk = blockIdx.x;
  const int tid = threadIdx.x;
  const int wid = __builtin_amdgcn_readfirstlane(tid >> 6);
  const int lane = tid & 63;
  const int cur = p & 1, prev = cur ^ 1;

  float* s0 = wf + FOFF_S0;  float* s1 = wf + FOFF_S1;
  float* s2 = wf + FOFF_S2;  float* s3 = wf + FOFF_S3;

  if (blk < 128) {           // L0: K=512, N=1024, E=8, A = x[t]
    int t = p; if (t >= NT) return;
    int rem = blk; int bh = rem & 1, stripe = rem >> 1;
    int b0 = bh << 6, b = b0 + lane;
    int o0 = stripe * 16 + wid * 8;
    float acc[8];
    gemm_wave<8>(x + (size_t)t * 512, (size_t)512 * 512, b0, W0, 512, o0, lds, acc);
    lif_ep<8, false>(acc, wf + FOFF_V0, 1024, 0.9f, 0.5f, b, o0,
                     s0 + (size_t)cur * 128 * 1024, nullptr, nullptr, 0);
  } else if (blk < 256) {    // L1: K=1024, N=1024, E=8, A = s0
    int t = p - 1; if (t < 0 || t >= NT) return;
    int rem = blk - 128; int bh = rem & 1, stripe = rem >> 1;
    int b0 = bh << 6, b = b0 + lane;
    int o0 = stripe * 16 + wid * 8;
    float acc[8];
    gemm_wave<8>(s0 + (size_t)prev * 128 * 1024, 1024, b0, W1, 1024, o0, lds, acc);
    lif_ep<8, false>(acc, wf + FOFF_V1, 1024, 0.95f, 0.5f, b, o0,
                     s1 + (size_t)cur * 128 * 1024, nullptr, nullptr, 0);
  } else if (blk < 512) {    // L2: two K=1024 gemms, N=1024, E=4
    int t = p - 2; if (t < 0 || t >= NT) return;
    int rem = blk - 256; int bh = rem & 1, stripe = rem >> 1;
    int b0 = bh << 6, b = b0 + lane;
    int o0 = stripe * 8 + wid * 4;
    float a1[4], a2[4];
    gemm_wave<4>(s1 + (size_t)prev * 128 * 1024, 1024, b0, W2a, 1024, o0, lds, a1);
    gemm_wave<4>(s2 + (size_t)prev * 128 * 1024, 1024, b0, W2b, 1024, o0, lds, a2);
    float cu[4];
#pragma unroll
    for (int e = 0; e < 4; ++e) cu[e] = __fadd_rn(a1[e], a2[e]);
    lif_ep<4, false>(cu, wf + FOFF_V2, 1024, 0.93f, 0.5f, b, o0,
                     s2 + (size_t)cur * 128 * 1024, nullptr, nullptr, 0);
  } else if (blk < 576) {    // L3: K=1024, N=512, E=8, A = s2
    int t = p - 3; if (t < 0 || t >= NT) return;
    int rem = blk - 512; int bh = rem & 1, stripe = rem >> 1;
    int b0 = bh << 6, b = b0 + lane;
    int o0 = stripe * 16 + wid * 8;
    float acc[8];
    gemm_wave<8>(s2 + (size_t)prev * 128 * 1024, 1024, b0, W3, 1024, o0, lds, acc);
    lif_ep<8, false>(acc, wf + FOFF_V3, 512, 0.9f, 0.5f, b, o0,
                     s3 + (size_t)cur * 128 * 512, nullptr, nullptr, 0);
  } else {                   // L4: K=512, N=128, E=8, A = s3, writes out
    int t = p - 4; if (t < 0 || t >= NT) return;
    int rem = blk - 576; int bh = rem & 1, stripe = rem >> 1;
    int b0 = bh << 6, b = b0 + lane;
    int o0 = stripe * 16 + wid * 8;
    float acc[8];
    gemm_wave<8>(s3 + (size_t)prev * 128 * 512, 512, b0, W4, 512, o0, lds, acc);
    lif_ep<8, true>(acc, wf + FOFF_VO, 128, 0.82f, 0.8f, b, o0,
                    nullptr, out, wf + FOFF_CNT, t);
  }
}

__global__ __launch_bounds__(256) void fin_kernel(const float* __restrict__ counts,
                                                  float* __restrict__ out) {
  int i = blockIdx.x * blockDim.x + threadIdx.x;
  if (i < 128 * 128) out[(size_t)128 * NT * 128 + i] = counts[i];
}

extern "C" void kernel_launch(void* const* d_in, const int* in_sizes, int n_in,
                              void* d_out, int out_size, void* d_ws, size_t ws_size,
                              hipStream_t stream) {
  const float* x   = (const float*)d_in[0];
  const float* W0  = (const float*)d_in[1];
  const float* W1  = (const float*)d_in[2];
  const float* W2a = (const float*)d_in[3];
  const float* W2b = (const float*)d_in[4];
  const float* W3  = (const float*)d_in[5];
  const float* W4  = (const float*)d_in[6];
  float* wf  = (float*)d_ws;
  float* out = (float*)d_out;

  init_kernel<<<256, 256, 0, stream>>>(wf);
  for (int p = 0; p < NT + 4; ++p) {
    phase_kernel<<<592, 128, 0, stream>>>(x, W0, W1, W2a, W2b, W3, W4, wf, out, p);
  }
  fin_kernel<<<64, 256, 0, stream>>>(wf + FOFF_CNT, out);
}